// Round 12
// baseline (164.853 us; speedup 1.0000x reference)
//
#include <hip/hip_runtime.h>
#include <math.h>

// Problem constants: B=8, N=2048, K=32, 9 bins, width 20.
#define BB 8
#define NN 2048
#define KK 32

// ===========================================================================
// Exactly-rounded f32 helpers (R15): native f32 _rn intrinsics. By Figueroa's
// theorem, (float)((double)a op (double)b) == correctly-rounded f32 op for
// +,-,*,/,sqrt — verified bit-identical on HW in R15 (absmax unchanged).
// ===========================================================================
__device__ __forceinline__ float fadd(float a, float b){ return __fadd_rn(a, b); }
__device__ __forceinline__ float fsub(float a, float b){ return __fsub_rn(a, b); }
__device__ __forceinline__ float fmul(float a, float b){ return __fmul_rn(a, b); }
__device__ __forceinline__ float fdiv(float a, float b){ return __fdiv_rn(a, b); }
__device__ __forceinline__ float fsqrtf32(float a){ return __fsqrt_rn(a); }

// ===========================================================================
// LAPACK 3.12 single-precision helpers, gfortran -ffp-contract=fast model.
// ===========================================================================
__device__ float slapy2f(float x, float y) {
    float xa = fabsf(x), ya = fabsf(y);
    float w = fmaxf(xa, ya), z = fminf(xa, ya);
    if (z == 0.0f) return w;
    float q = fdiv(z, w);
    return fmul(w, fsqrtf32(fmaf(q, q, 1.0f)));
}

__device__ void slartgf(float f, float g, float& c, float& s, float& r) {
    if (g == 0.0f) { c = 1.0f; s = 0.0f; r = f; }
    else if (f == 0.0f) { c = 0.0f; s = copysignf(1.0f, g); r = fabsf(g); }
    else {
        float d = fsqrtf32(fmaf(f, f, fmul(g, g)));
        c = fdiv(fabsf(f), d);
        r = copysignf(d, f);
        s = fdiv(g, r);
    }
}

__device__ void slas2f(float f, float g, float h, float& ssmin, float& ssmax) {
    float fa = fabsf(f), ga = fabsf(g), ha = fabsf(h);
    float fhmn = fminf(fa, ha), fhmx = fmaxf(fa, ha);
    if (fhmn == 0.0f) {
        ssmin = 0.0f;
        if (fhmx == 0.0f) ssmax = ga;
        else {
            float mx = fmaxf(fhmx, ga), mn = fminf(fhmx, ga);
            float q = fdiv(mn, mx);
            ssmax = fmul(mx, fsqrtf32(fmaf(q, q, 1.0f)));
        }
    } else {
        if (ga < fhmx) {
            float as = fadd(1.0f, fdiv(fhmn, fhmx));
            float at = fdiv(fsub(fhmx, fhmn), fhmx);
            float q = fdiv(ga, fhmx); float au = fmul(q, q);
            float c = fdiv(2.0f, fadd(fsqrtf32(fmaf(as, as, au)),
                                      fsqrtf32(fmaf(at, at, au))));
            ssmin = fmul(fhmn, c); ssmax = fdiv(fhmx, c);
        } else {
            float au = fdiv(fhmx, ga);
            if (au == 0.0f) { ssmin = fdiv(fmul(fhmn, fhmx), ga); ssmax = ga; }
            else {
                float as = fadd(1.0f, fdiv(fhmn, fhmx));
                float at = fdiv(fsub(fhmx, fhmn), fhmx);
                float t1 = fmul(as, au), t2 = fmul(at, au);
                float c = fdiv(1.0f, fadd(fsqrtf32(fmaf(t1, t1, 1.0f)),
                                          fsqrtf32(fmaf(t2, t2, 1.0f))));
                ssmin = fmul(fmul(fhmn, c), au); ssmin = fadd(ssmin, ssmin);
                ssmax = fdiv(ga, fadd(c, c));
            }
        }
    }
}

__device__ void slasv2f(float f, float g, float h,
                        float& ssmin, float& ssmax,
                        float& snr, float& csr, float& snl, float& csl) {
    const float eps = 5.9604644775390625e-08f;
    float ft = f, fa = fabsf(f), ht = h, ha = fabsf(h);
    int pmax = 1;
    bool swp = (ha > fa);
    if (swp) { pmax = 3; float t = ft; ft = ht; ht = t; t = fa; fa = ha; ha = t; }
    float gt = g, ga = fabsf(gt);
    float clt = 0.f, crt = 0.f, slt = 0.f, srt = 0.f;
    if (ga == 0.0f) {
        ssmin = ha; ssmax = fa; clt = 1.0f; crt = 1.0f; slt = 0.0f; srt = 0.0f;
    } else {
        bool gasmal = true;
        if (ga > fa) {
            pmax = 2;
            if (fdiv(fa, ga) < eps) {
                gasmal = false;
                ssmax = ga;
                ssmin = (ha > 1.0f) ? fdiv(fa, fdiv(ga, ha)) : fmul(fdiv(fa, ga), ha);
                clt = 1.0f; slt = fdiv(ht, gt); srt = 1.0f; crt = fdiv(ft, gt);
            }
        }
        if (gasmal) {
            float dd = fsub(fa, ha);
            float l = (dd == fa) ? 1.0f : fdiv(dd, fa);
            float mm = fdiv(gt, ft);
            float t = fsub(2.0f, l);
            float m2 = fmul(mm, mm);
            float s = fsqrtf32(fmaf(t, t, m2));
            float r = (l == 0.0f) ? fabsf(mm) : fsqrtf32(fmaf(l, l, m2));
            float a = fmul(0.5f, fadd(s, r));
            ssmin = fdiv(ha, a);
            ssmax = fmul(fa, a);
            if (m2 == 0.0f) {
                t = (l == 0.0f) ? fmul(copysignf(2.0f, ft), copysignf(1.0f, gt))
                                : fadd(fdiv(gt, copysignf(dd, ft)), fdiv(mm, t));
            } else {
                t = fmul(fadd(fdiv(mm, fadd(s, t)), fdiv(mm, fadd(r, l))), fadd(1.0f, a));
            }
            float l2 = fsqrtf32(fmaf(t, t, 4.0f));
            crt = fdiv(2.0f, l2); srt = fdiv(t, l2);
            clt = fdiv(fmaf(srt, mm, crt), a);
            slt = fdiv(fmul(fdiv(ht, ft), srt), a);
        }
    }
    if (swp) { csl = srt; snl = crt; csr = slt; snr = clt; }
    else     { csl = clt; snl = slt; csr = crt; snr = srt; }
    float tsign = 0.0f;
    if (pmax == 1) tsign = fmul(fmul(copysignf(1.f, csr), copysignf(1.f, csl)), copysignf(1.f, f));
    if (pmax == 2) tsign = fmul(fmul(copysignf(1.f, snr), copysignf(1.f, csl)), copysignf(1.f, g));
    if (pmax == 3) tsign = fmul(fmul(copysignf(1.f, snr), copysignf(1.f, snl)), copysignf(1.f, h));
    ssmax = copysignf(fabsf(ssmax), tsign);
    ssmin = copysignf(fabsf(ssmin), fmul(tsign, fmul(copysignf(1.f, f), copysignf(1.f, h))));
}

// slasr 'L','V' rotation on vt rows lo,hi (1-indexed), fma-contracted
__device__ __forceinline__ void rot_rowsf(float vt[4][4], int lo, int hi, float cc, float ss) {
    #pragma unroll
    for (int c = 1; c <= 3; ++c) {
        float t = vt[hi][c];
        vt[hi][c] = fmaf(cc, t, -fmul(ss, vt[lo][c]));
        vt[lo][c] = fmaf(ss, t, fmul(cc, vt[lo][c]));
    }
}

// sbdsqr for n=3 upper bidiagonal — R16/R18 array version (R17's select-chain
// rewrite regressed ~12 µs; the small hot stack arrays are L1-resident).
// R9 note: idir2-shifted VT pairing is (COSL, -SINL) — do not touch.
__device__ void bdsqr3f(float* d, float* e, float vt[4][4]) {
    const float eps  = 5.9604644775390625e-08f;
    const float unfl = 1.1754943508222875e-38f;
    const int n = 3;
    const float tol = fmul(10.0f, eps);
    float thresh;
    {
        float sminoa = fabsf(d[1]);
        if (sminoa != 0.0f) {
            float mu = sminoa;
            for (int i = 2; i <= n; ++i) {
                mu = fmul(fabsf(d[i]), fdiv(mu, fadd(mu, fabsf(e[i - 1]))));
                sminoa = fminf(sminoa, mu);
                if (sminoa == 0.0f) break;
            }
        }
        sminoa = fdiv(sminoa, fsqrtf32(3.0f));
        thresh = fmaxf(fmul(tol, sminoa), fmul(54.0f, unfl));
    }
    int m = n, iter = 0, oldll = -1, oldm = -1, idir = 0;
    float sminl = 0.0f;
    while (m > 1) {
        if (iter > 54) break;
        float smax = fabsf(d[m]);
        int ll = 0; bool split = false;
        for (int lll = 1; lll <= m - 1; ++lll) {
            int l2 = m - lll;
            float abss = fabsf(d[l2]), abse = fabsf(e[l2]);
            if (abse <= thresh) { ll = l2; split = true; break; }
            smax = fmaxf(smax, fmaxf(abss, abse));
        }
        if (split) {
            e[ll] = 0.0f;
            if (ll == m - 1) { m = m - 1; continue; }
            ll = ll + 1;
        } else ll = 1;
        if (ll == m - 1) {
            float sigmn, sigmx, sinr, cosr, sinl, cosl;
            slasv2f(d[m - 1], e[m - 1], d[m], sigmn, sigmx, sinr, cosr, sinl, cosl);
            d[m - 1] = sigmx; e[m - 1] = 0.0f; d[m] = sigmn;
            #pragma unroll
            for (int c = 1; c <= 3; ++c) {
                float t = fmaf(cosr, vt[m - 1][c], fmul(sinr, vt[m][c]));
                vt[m][c] = fmaf(cosr, vt[m][c], -fmul(sinr, vt[m - 1][c]));
                vt[m - 1][c] = t;
            }
            m -= 2; continue;
        }
        if (ll > oldm || m < oldll)
            idir = (fabsf(d[ll]) >= fabsf(d[m])) ? 1 : 2;
        bool deflated = false;
        if (idir == 1) {
            if (fabsf(e[m - 1]) <= fmul(tol, fabsf(d[m]))) { e[m - 1] = 0.0f; continue; }
            float mu = fabsf(d[ll]); sminl = mu;
            for (int lll = ll; lll <= m - 1; ++lll) {
                if (fabsf(e[lll]) <= fmul(tol, mu)) { e[lll] = 0.0f; deflated = true; break; }
                mu = fmul(fabsf(d[lll + 1]), fdiv(mu, fadd(mu, fabsf(e[lll]))));
                sminl = fminf(sminl, mu);
            }
        } else {
            if (fabsf(e[ll]) <= fmul(tol, fabsf(d[ll]))) { e[ll] = 0.0f; continue; }
            float mu = fabsf(d[m]); sminl = mu;
            for (int lll = m - 1; lll >= ll; --lll) {
                if (fabsf(e[lll]) <= fmul(tol, mu)) { e[lll] = 0.0f; deflated = true; break; }
                mu = fmul(fabsf(d[lll]), fdiv(mu, fadd(mu, fabsf(e[lll]))));
                sminl = fminf(sminl, mu);
            }
        }
        if (deflated) continue;
        oldll = ll; oldm = m;
        float shift = 0.0f, rr;
        if (!(fmul(fmul(3.0f, tol), fdiv(sminl, smax)) <= fmaxf(eps, fmul(0.01f, tol)))) {
            float sll;
            if (idir == 1) { sll = fabsf(d[ll]); slas2f(d[m - 1], e[m - 1], d[m], shift, rr); }
            else           { sll = fabsf(d[m]);  slas2f(d[ll], e[ll], d[ll + 1], shift, rr); }
            if (sll > 0.0f) { float q = fdiv(shift, sll); if (fmul(q, q) < eps) shift = 0.0f; }
        }
        iter += m - ll;
        float wc[4], ws[4];
        if (shift == 0.0f) {
            if (idir == 1) {
                float cs = 1.0f, oldcs = 1.0f, sn = 0.0f, oldsn = 0.0f, r2;
                for (int i = ll; i <= m - 1; ++i) {
                    slartgf(fmul(d[i], cs), e[i], cs, sn, r2);
                    if (i > ll) e[i - 1] = fmul(oldsn, r2);
                    slartgf(fmul(oldcs, r2), fmul(d[i + 1], sn), oldcs, oldsn, d[i]);
                    wc[i - ll + 1] = cs; ws[i - ll + 1] = sn;
                }
                float h = fmul(d[m], cs); d[m] = fmul(h, oldcs); e[m - 1] = fmul(h, oldsn);
                if (fabsf(e[m - 1]) <= thresh) e[m - 1] = 0.0f;
                for (int j = 1; j <= m - ll; ++j) rot_rowsf(vt, ll + j - 1, ll + j, wc[j], ws[j]);
            } else {
                float cs = 1.0f, oldcs = 1.0f, sn = 0.0f, oldsn = 0.0f, r2;
                for (int i = m; i >= ll + 1; --i) {
                    slartgf(fmul(d[i], cs), e[i - 1], cs, sn, r2);
                    if (i < m) e[i] = fmul(oldsn, r2);
                    slartgf(fmul(oldcs, r2), fmul(d[i - 1], sn), oldcs, oldsn, d[i]);
                    wc[i - ll] = oldcs; ws[i - ll] = -oldsn;
                }
                float h = fmul(d[ll], cs); d[ll] = fmul(h, oldcs); e[ll] = fmul(h, oldsn);
                if (fabsf(e[ll]) <= thresh) e[ll] = 0.0f;
                for (int j = m - ll; j >= 1; --j) rot_rowsf(vt, ll + j - 1, ll + j, wc[j], ws[j]);
            }
        } else {
            if (idir == 1) {
                float fq = fmul(fsub(fabsf(d[ll]), shift),
                                fadd(copysignf(1.0f, d[ll]), fdiv(shift, d[ll])));
                float g = e[ll], cosr, sinr, cosl, sinl, r2;
                for (int i = ll; i <= m - 1; ++i) {
                    slartgf(fq, g, cosr, sinr, r2);
                    if (i > ll) e[i - 1] = r2;
                    float di = d[i], ei = e[i], dip = d[i + 1];
                    fq         = fmaf(cosr, di, fmul(sinr, ei));
                    float ei_n = fmaf(cosr, ei, -fmul(sinr, di));
                    g = fmul(sinr, dip);
                    float dip_n = fmul(cosr, dip);
                    slartgf(fq, g, cosl, sinl, r2);
                    d[i] = r2;
                    fq       = fmaf(cosl, ei_n, fmul(sinl, dip_n));
                    d[i + 1] = fmaf(cosl, dip_n, -fmul(sinl, ei_n));
                    e[i] = ei_n;
                    if (i < m - 1) { g = fmul(sinl, e[i + 1]); e[i + 1] = fmul(cosl, e[i + 1]); }
                    wc[i - ll + 1] = cosr; ws[i - ll + 1] = sinr;
                }
                e[m - 1] = fq;
                if (fabsf(e[m - 1]) <= thresh) e[m - 1] = 0.0f;
                for (int j = 1; j <= m - ll; ++j) rot_rowsf(vt, ll + j - 1, ll + j, wc[j], ws[j]);
            } else {
                float fq = fmul(fsub(fabsf(d[m]), shift),
                                fadd(copysignf(1.0f, d[m]), fdiv(shift, d[m])));
                float g = e[m - 1], cosr, sinr, cosl, sinl, r2;
                for (int i = m; i >= ll + 1; --i) {
                    slartgf(fq, g, cosr, sinr, r2);
                    if (i < m) e[i] = r2;
                    float di = d[i], em = e[i - 1], dim = d[i - 1];
                    fq         = fmaf(cosr, di, fmul(sinr, em));
                    float em_n = fmaf(cosr, em, -fmul(sinr, di));
                    g = fmul(sinr, dim);
                    float dim_n = fmul(cosr, dim);
                    slartgf(fq, g, cosl, sinl, r2);
                    d[i] = r2;
                    fq       = fmaf(cosl, em_n, fmul(sinl, dim_n));
                    d[i - 1] = fmaf(cosl, dim_n, -fmul(sinl, em_n));
                    e[i - 1] = em_n;
                    if (i > ll + 1) { g = fmul(sinl, e[i - 2]); e[i - 2] = fmul(cosl, e[i - 2]); }
                    wc[i - ll] = cosl; ws[i - ll] = -sinl;   // R9-verified pairing
                }
                e[ll] = fq;
                if (fabsf(e[ll]) <= thresh) e[ll] = 0.0f;
                for (int j = m - ll; j >= 1; --j) rot_rowsf(vt, ll + j - 1, ll + j, wc[j], ws[j]);
            }
        }
    }
    for (int i = 1; i <= n; ++i) {
        if (d[i] < 0.0f) {
            d[i] = -d[i];
            for (int c = 1; c <= 3; ++c) vt[i][c] = -vt[i][c];
        }
    }
    for (int i = 1; i <= n - 1; ++i) {
        int isub = 1; float smin2 = d[1];
        for (int j = 2; j <= n + 1 - i; ++j)
            if (d[j] <= smin2) { isub = j; smin2 = d[j]; }
        int tgt = n + 1 - i;
        if (isub != tgt) {
            d[isub] = d[tgt]; d[tgt] = smin2;
            for (int c = 1; c <= 3; ++c) { float t = vt[isub][c]; vt[isub][c] = vt[tgt][c]; vt[tgt][c] = t; }
        }
    }
}

// ===========================================================================
// Kernel 0: d2 in f32 (separate — R16's knn-inline regressed knn 81->93)
// ===========================================================================
__global__ void d2_kernel(const float* __restrict__ x, float* __restrict__ d2) {
    int t = blockIdx.x * blockDim.x + threadIdx.x;
    if (t >= BB * NN) return;
    int b = t / NN, n = t % NN;
    const float* xb = x + b * 3 * NN;
    float xv = xb[n], yv = xb[NN + n], zv = xb[2 * NN + n];
    d2[t] = fadd(fadd(fmul(xv, xv), fmul(yv, yv)), fmul(zv, zv));
}

// ===========================================================================
// Kernel 1: KNN — R20 (resubmitted R21; R20 bench was an infra failure):
// BRANCHLESS tie resolution + peeled first 4 iters.
//
// R19 post-mortem: ballot/popc/ffs/branch fast path dropped VALUBusy 96->66%
// (serial VALU->SALU->branch chain stalls instead of issuing). R20 replaces
// it with a second 32-bit DPP cascade on tl = (l0h==wbest)? l0l : 0 —
// 13 straight-line VALU ops, no scalar round-trips. Semantics: max l0l among
// value-tied lanes = min j = exact u64-max order; live l0l words are
// globally unique (sentinel (0,0) only ever at l1-l3, never compared;
// post-refill low words unique by construction) => bit-identical sequence.
// Refill check peeled: a lane can exhaust its 4-deep lookahead only after 4
// wins, so iterations 0-3 provably never refill.
// ===========================================================================
__device__ __forceinline__ unsigned int f32_sortable(float f) {
    unsigned int b = __float_as_uint(f);
    return b ^ ((unsigned int)((int)b >> 31) | 0x80000000u);
}
__device__ __forceinline__ float sortable_f32(unsigned int s) {
    unsigned int b = s ^ (~(unsigned int)((int)s >> 31) | 0x80000000u);
    return __uint_as_float(b);
}

template <int CTRL, int RM>
__device__ __forceinline__ unsigned int dpp_umax32(unsigned int v) {
    unsigned int nv = (unsigned int)__builtin_amdgcn_update_dpp(0, (int)v, CTRL, RM, 0xF, false);
    return nv > v ? nv : v;
}

// full 6-stage cascade: lane 63 ends with the wave-wide max
__device__ __forceinline__ unsigned int wave_umax32(unsigned int v) {
    v = dpp_umax32<0x111, 0xF>(v);   // row_shr:1
    v = dpp_umax32<0x112, 0xF>(v);   // row_shr:2
    v = dpp_umax32<0x114, 0xF>(v);   // row_shr:4
    v = dpp_umax32<0x118, 0xF>(v);   // row_shr:8
    v = dpp_umax32<0x142, 0xA>(v);   // row_bcast:15 -> rows 1,3
    v = dpp_umax32<0x143, 0xC>(v);   // row_bcast:31 -> rows 2,3
    return v;
}

// Pop the lane's best remaining candidate from vals (value desc, slot asc),
// clear it, and return the packed u64 merge key. All indices static.
__device__ __forceinline__ unsigned long long pop_best(unsigned int (&vals)[32], int lane) {
    unsigned int m = vals[0];
    #pragma unroll
    for (int s = 1; s < 32; ++s) m = (vals[s] > m) ? vals[s] : m;   // v_max_u32
    int bs = 0;
    #pragma unroll
    for (int s = 31; s >= 0; --s) if (vals[s] == m) bs = s;          // first match
    #pragma unroll
    for (int s = 0; s < 32; ++s) vals[s] = (s == bs) ? 0u : vals[s]; // clear
    int j = bs * 64 + lane;
    return ((unsigned long long)m << 32) | (unsigned int)(2047 - j);
}

__global__ void __launch_bounds__(256) knn_kernel(const float* __restrict__ x,
                                                  const float* __restrict__ d2,
                                                  int* __restrict__ idx) {
    int lane = threadIdx.x & 63;
    int wid  = threadIdx.x >> 6;
    int row  = blockIdx.x * 4 + wid;
    int b = row / NN, i = row % NN;
    const float* xb  = x  + b * 3 * NN;
    const float* d2b = d2 + b * NN;

    float xi = xb[i], yi = xb[NN + i], zi = xb[2 * NN + i];
    float d2i = d2b[i];

    // 32 candidates per lane, sortable-u32 encoded, static register indexing.
    unsigned int vals[32];
    #pragma unroll
    for (int s = 0; s < 32; ++s) {
        int j = s * 64 + lane;
        float dot = fmul(xi, xb[j]);
        dot = fmaf(yi, xb[NN + j], dot);
        dot = fmaf(zi, xb[2 * NN + j], dot);
        float v = fsub(fsub(fmul(2.0f, dot), d2i), d2b[j]);
        vals[s] = f32_sortable(v);
    }

    // ---- build the 4-deep lookahead mini-list (hi/lo u32 named scalars)
    unsigned long long p;
    p = pop_best(vals, lane);
    unsigned int l0h = (unsigned int)(p >> 32), l0l = (unsigned int)p;
    p = pop_best(vals, lane);
    unsigned int l1h = (unsigned int)(p >> 32), l1l = (unsigned int)p;
    p = pop_best(vals, lane);
    unsigned int l2h = (unsigned int)(p >> 32), l2l = (unsigned int)p;
    p = pop_best(vals, lane);
    unsigned int l3h = (unsigned int)(p >> 32), l3l = (unsigned int)p;

    int* idxrow = idx + row * KK;
    unsigned int c1v = 0, c2v = 0, c3v = 0, c31v = 0, c32v = 0;
    int c1i = 0, c2i = 0, c3i = 0, c31i = 0, c32i = 0;

    #pragma unroll 1
    for (int t = 0; t < KK + 1; ++t) {      // 33 ranks (32 + boundary probe)
        // refill check dead for t<4 (a lane must win 4x to exhaust lookahead)
        if (t >= 4 && __any(l0h == 0u)) {
            bool need = (l0h == 0u);
            unsigned int m = vals[0];
            #pragma unroll
            for (int s = 1; s < 32; ++s) m = (vals[s] > m) ? vals[s] : m;
            int bs = 0;
            #pragma unroll
            for (int s = 31; s >= 0; --s) if (vals[s] == m) bs = s;
            #pragma unroll
            for (int s = 0; s < 32; ++s)
                vals[s] = (need && s == bs) ? 0u : vals[s];
            unsigned int enth = m;
            unsigned int entl = (unsigned int)(2047 - (bs * 64 + lane));
            l0h = need ? enth : l0h;
            l0l = need ? entl : l0l;
        }

        // wave max of the VALUE word (32-bit DPP cascade)
        unsigned int wbest = (unsigned int)__builtin_amdgcn_readlane(
            (int)wave_umax32(l0h), 63);

        // branchless tie resolution: max l0l among value-tied lanes
        // (= min j = exact u64-max order); straight-line VALU, no SALU chain
        unsigned int tl = (l0h == wbest) ? l0l : 0u;
        unsigned int wlow = (unsigned int)__builtin_amdgcn_readlane(
            (int)wave_umax32(tl), 63);
        int wj = 2047 - (int)(wlow & 0x7FFu);

        // winner lane pops its head (live keylow globally unique => 1 cmp).
        bool amw = (l0l == wlow);
        l0h = amw ? l1h : l0h;  l0l = amw ? l1l : l0l;
        l1h = amw ? l2h : l1h;  l1l = amw ? l2l : l1l;
        l2h = amw ? l3h : l2h;  l2l = amw ? l3l : l2l;
        l3h = amw ? 0u  : l3h;  l3l = amw ? 0u  : l3l;

        // record: ranks 1,2,3,31,32 are deferred for the near-tie probes
        if (t == 1)           { c1v = wbest;  c1i = wj; }
        else if (t == 2)      { c2v = wbest;  c2i = wj; }
        else if (t == 3)      { c3v = wbest;  c3i = wj; }
        else if (t == KK - 1) { c31v = wbest; c31i = wj; }
        else if (t == KK)     { c32v = wbest; c32i = wj; }
        else if (lane == 0)   idxrow[t] = wj;
    }

    if (lane == 0) {
        const float TIE = 4e-7f;
        float r1  = sortable_f32(c1v),  r2  = sortable_f32(c2v), r3 = sortable_f32(c3v);
        float r31 = sortable_f32(c31v), r32 = sortable_f32(c32v);
        if (fabsf(r1 - r2) < TIE) { int ti = c1i; c1i = c2i; c2i = ti; float tv = r1; r1 = r2; r2 = tv; }
        if (fabsf(r2 - r3) < TIE) { int ti = c2i; c2i = c3i; c3i = ti; float tv = r2; r2 = r3; r3 = tv; }
        idxrow[1] = c1i; idxrow[2] = c2i; idxrow[3] = c3i;
        idxrow[KK - 1] = (fabsf(r31 - r32) < TIE) ? c32i : c31i;
    }
}

// ===========================================================================
// Kernel 2: sgesdd emulation + fused vote precompute (R19 structure:
// coordinates loaded once into A0/A1/A2, bit-identical op order).
// ===========================================================================
__global__ void eig_kernel(const float* __restrict__ x, const int* __restrict__ idx,
                           float4* __restrict__ votes, int* __restrict__ binsq) {
    int t = blockIdx.x * blockDim.x + threadIdx.x;
    if (t >= BB * NN) return;
    int b = t / NN;
    const float* xb = x + b * 3 * NN;
    const int* id = idx + t * KK;

    float A0[KK], A1[KK], A2[KK];
    #pragma unroll
    for (int j = 0; j < KK; ++j) {
        int n = id[j];
        A0[j] = xb[n];
        A1[j] = xb[NN + n];
        A2[j] = xb[2 * NN + n];
    }
    float s0 = 0.f, s1 = 0.f, s2 = 0.f;
    #pragma unroll
    for (int j = 0; j < KK; ++j) {
        s0 = fadd(s0, A0[j]); s1 = fadd(s1, A1[j]); s2 = fadd(s2, A2[j]);
    }
    float m0 = fdiv(s0, 32.f), m1 = fdiv(s1, 32.f), m2 = fdiv(s2, 32.f);
    #pragma unroll
    for (int j = 0; j < KK; ++j) {
        A0[j] = fsub(A0[j], m0);
        A1[j] = fsub(A1[j], m1);
        A2[j] = fsub(A2[j], m2);
    }

    // ---- sgeqr2 with slarf1f (i = 0: col0 reflector, update col1,col2)
    {
        float alpha = A0[0];
        double nacc = 0.0;
        #pragma unroll
        for (int r = 1; r < KK; ++r) nacc += (double)A0[r] * (double)A0[r];
        float xnorm = (float)sqrt(nacc);
        if (xnorm != 0.0f) {
            float beta = -copysignf(slapy2f(alpha, xnorm), alpha);
            float tau  = fdiv(fsub(beta, alpha), beta);
            float scal = fdiv(1.0f, fsub(alpha, beta));
            #pragma unroll
            for (int r = 1; r < KK; ++r) A0[r] = fmul(A0[r], scal);
            A0[0] = beta;
            // j = 1
            {
                float acc = 0.0f;
                #pragma unroll
                for (int r = 1; r < KK; ++r) acc = fmaf(A0[r], A1[r], acc);
                float w = fadd(acc, A1[0]);
                A1[0] = fmaf(-tau, w, A1[0]);
                float temp = fmul(-tau, w);
                #pragma unroll
                for (int r = 1; r < KK; ++r) A1[r] = fmaf(A0[r], temp, A1[r]);
            }
            // j = 2
            {
                float acc = 0.0f;
                #pragma unroll
                for (int r = 1; r < KK; ++r) acc = fmaf(A0[r], A2[r], acc);
                float w = fadd(acc, A2[0]);
                A2[0] = fmaf(-tau, w, A2[0]);
                float temp = fmul(-tau, w);
                #pragma unroll
                for (int r = 1; r < KK; ++r) A2[r] = fmaf(A0[r], temp, A2[r]);
            }
        }
    }
    // ---- i = 1: col1 reflector, update col2
    {
        float alpha = A1[1];
        double nacc = 0.0;
        #pragma unroll
        for (int r = 2; r < KK; ++r) nacc += (double)A1[r] * (double)A1[r];
        float xnorm = (float)sqrt(nacc);
        if (xnorm != 0.0f) {
            float beta = -copysignf(slapy2f(alpha, xnorm), alpha);
            float tau  = fdiv(fsub(beta, alpha), beta);
            float scal = fdiv(1.0f, fsub(alpha, beta));
            #pragma unroll
            for (int r = 2; r < KK; ++r) A1[r] = fmul(A1[r], scal);
            A1[1] = beta;
            // j = 2
            {
                float acc = 0.0f;
                #pragma unroll
                for (int r = 2; r < KK; ++r) acc = fmaf(A1[r], A2[r], acc);
                float w = fadd(acc, A2[1]);
                A2[1] = fmaf(-tau, w, A2[1]);
                float temp = fmul(-tau, w);
                #pragma unroll
                for (int r = 2; r < KK; ++r) A2[r] = fmaf(A1[r], temp, A2[r]);
            }
        }
    }
    // ---- i = 2: col2 reflector (no trailing columns)
    {
        float alpha = A2[2];
        double nacc = 0.0;
        #pragma unroll
        for (int r = 3; r < KK; ++r) nacc += (double)A2[r] * (double)A2[r];
        float xnorm = (float)sqrt(nacc);
        if (xnorm != 0.0f) {
            float beta = -copysignf(slapy2f(alpha, xnorm), alpha);
            float scal = fdiv(1.0f, fsub(alpha, beta));
            #pragma unroll
            for (int r = 3; r < KK; ++r) A2[r] = fmul(A2[r], scal);
            A2[2] = beta;
        }
    }
    float B11 = A0[0], B12 = A1[0], B13 = A2[0];
    float B22 = A1[1], B23 = A2[1], B33 = A2[2];

    // ---- sgebd2 with slarf1f
    float d[4], e[3];
    float taup = 0.0f, v2p = 0.0f;
    d[1] = B11;
    float B32 = 0.0f;
    if (B13 != 0.0f) {
        float xn = fsqrtf32(fmul(B13, B13));
        float beta = -copysignf(slapy2f(B12, xn), B12);
        taup = fdiv(fsub(beta, B12), beta);
        float scal = fdiv(1.0f, fsub(B12, beta));
        v2p = fmul(B13, scal);
        e[1] = beta;
        float w2 = fadd(fmul(B23, v2p), B22);
        float w3 = fmul(B33, v2p);
        B22 = fmaf(-taup, w2, B22);
        B32 = fmul(-taup, w3);
        float tmp = fmul(-taup, v2p);
        B23 = fmaf(w2, tmp, B23);
        B33 = fmaf(w3, tmp, B33);
    } else e[1] = B12;
    if (B32 != 0.0f) {
        float xn = fsqrtf32(fmul(B32, B32));
        float beta = -copysignf(slapy2f(B22, xn), B22);
        float tauq = fdiv(fsub(beta, B22), beta);
        float scal = fdiv(1.0f, fsub(B22, beta));
        float v2 = fmul(B32, scal);
        d[2] = beta;
        float w = fadd(fmul(v2, B33), B23);
        B23 = fmaf(-tauq, w, B23);
        float tmp = fmul(-tauq, w);
        B33 = fmaf(v2, tmp, B33);
    } else d[2] = B22;
    e[2] = B23;
    d[3] = B33;

    // ---- sbdsqr with VT = I
    float vt[4][4];
    for (int r = 1; r <= 3; ++r)
        for (int c = 1; c <= 3; ++c) vt[r][c] = (r == c) ? 1.0f : 0.0f;
    bdsqr3f(d, e, vt);

    // ---- sormbr 'P','R','T' via slarf1f
    if (taup != 0.0f) {
        float tmp = fmul(-taup, v2p);
        for (int r = 1; r <= 3; ++r) {
            float w = fadd(fmul(vt[r][3], v2p), vt[r][2]);
            vt[r][2] = fmaf(-taup, w, vt[r][2]);
            vt[r][3] = fmaf(w, tmp, vt[r][3]);
        }
    }

    int im = 1;
    if (d[2] > d[im]) im = 2;
    if (d[3] > d[im]) im = 3;
    float gx = vt[im][1];
    float gy = vt[im][2];
    float gz = vt[im][3];
    float m  = fsqrtf32(d[im]);

    // ---- fused vote precompute (identical ops to the old vote_kernel)
    const float r2d = (float)(180.0 / M_PI);
    float zen = (float)acos((double)gz);
    float zd  = fmul(zen, r2d);
    float q0  = fdiv(gy, gx);
    float azr = (float)atan((double)q0);
    float ad  = fmul(azr, r2d);

    float a0 = (zd != zd) ? -2147483648.0f : (float)(int)zd;
    float a1 = (ad != ad) ? -2147483648.0f : (float)(int)ad;

    float v1s[2], v2s[2]; int bis[2];
    #pragma unroll
    for (int c = 0; c < 2; ++c) {
        float a = (c == 0) ? a0 : a1;
        if (a < 0.0f) a = fadd(a, 180.0f);
        float tq = fdiv(a, 20.0f);
        float t2 = fsub(tq, 0.5f);
        float fb = floorf(t2);
        float bin = fmodf(fb, 9.0f); if (bin != 0.0f && bin < 0.0f) bin = fadd(bin, 9.0f);
        float b1 = fadd(bin, 1.0f);
        float b1m = fmodf(b1, 9.0f);
        float fc = fmul(20.0f, fadd(b1m, 0.5f));
        float df = fsub(fc, a);
        float rm = fmodf(df, 180.0f); if (rm != 0.0f && rm < 0.0f) rm = fadd(rm, 180.0f);
        v1s[c] = fdiv(fmul(m, rm), 20.0f);
        float sc = fmul(20.0f, fadd(bin, 0.5f));
        float ds = fsub(a, sc);
        float rm2 = fmodf(ds, 180.0f); if (rm2 != 0.0f && rm2 < 0.0f) rm2 = fadd(rm2, 180.0f);
        v2s[c] = fdiv(fmul(m, rm2), 20.0f);
        bis[c] = (int)bin;
    }
    votes[t] = make_float4(v1s[0], v2s[0], v1s[1], v2s[1]);
    binsq[t] = bis[0] | (bis[1] << 8);
}

// ===========================================================================
// Kernel 3: HOG accumulation (R16 static-register version, R19 unroll-8 —
// bit-identical j-ascending add order, fully static indices => registers).
// ===========================================================================
__global__ void hist_kernel(const int* __restrict__ idx, const float4* __restrict__ votes,
                            const int* __restrict__ binsq, float* __restrict__ out) {
    int t = blockIdx.x * blockDim.x + threadIdx.x;
    if (t >= BB * NN) return;
    int b = t / NN, n = t % NN;
    const int* id = idx + t * KK;

    float h1[9][2], h2[9][2];
    #pragma unroll
    for (int q = 0; q < 9; ++q) { h1[q][0] = h1[q][1] = 0.f; h2[q][0] = h2[q][1] = 0.f; }

    #pragma unroll 8
    for (int j = 0; j < KK; ++j) {
        int jj = b * NN + id[j];
        float4 v = votes[jj];
        int bp = binsq[jj];
        int bi0 = bp & 0xFF, bi1 = bp >> 8;
        int b20 = bi0 + 1; if (b20 >= 9) b20 -= 9;
        int b21 = bi1 + 1; if (b21 >= 9) b21 -= 9;
        #pragma unroll
        for (int q = 0; q < 9; ++q) {
            h1[q][0] = (bi0 == q) ? fadd(h1[q][0], v.x) : h1[q][0];
            h2[q][0] = (b20 == q) ? fadd(h2[q][0], v.y) : h2[q][0];
            h1[q][1] = (bi1 == q) ? fadd(h1[q][1], v.z) : h1[q][1];
            h2[q][1] = (b21 == q) ? fadd(h2[q][1], v.w) : h2[q][1];
        }
    }

    float* o = out + b * (18 * NN) + n * 18;
    #pragma unroll
    for (int c = 0; c < 2; ++c) {
        float hist[9];
        #pragma unroll
        for (int q = 0; q < 9; ++q) hist[q] = fadd(h1[q][c], h2[q][c]);
        float acc = 0.0f;
        #pragma unroll
        for (int q = 0; q < 9; ++q) acc = fadd(acc, fmul(hist[q], hist[q]));
        float nr = fsqrtf32(acc);
        float den = fmaxf(nr, 1e-12f);
        #pragma unroll
        for (int q = 0; q < 9; ++q) o[q * 2 + c] = fdiv(hist[q], den);
    }
}

// ===========================================================================
extern "C" void kernel_launch(void* const* d_in, const int* in_sizes, int n_in,
                              void* d_out, int out_size, void* d_ws, size_t ws_size,
                              hipStream_t stream) {
    const float* x = (const float*)d_in[0];
    float* out = (float*)d_out;

    char* ws = (char*)d_ws;
    size_t off = 0;
    int* idx = (int*)(ws + off);         off += (size_t)BB * NN * KK * sizeof(int);
    float* d2 = (float*)(ws + off);      off += (size_t)BB * NN * sizeof(float);
    float4* votes = (float4*)(ws + off); off += (size_t)BB * NN * sizeof(float4);
    int* binsq = (int*)(ws + off);

    d2_kernel  <<<(BB * NN + 63) / 64, 64, 0, stream>>>(x, d2);
    knn_kernel <<<BB * NN / 4, 256, 0, stream>>>(x, d2, idx);
    eig_kernel <<<(BB * NN + 63) / 64, 64, 0, stream>>>(x, idx, votes, binsq);
    hist_kernel<<<(BB * NN + 63) / 64, 64, 0, stream>>>(idx, votes, binsq, out);
}

// Round 13
// 162.416 us; speedup vs baseline: 1.0150x; 1.0150x over previous
//
#include <hip/hip_runtime.h>
#include <math.h>

// Problem constants: B=8, N=2048, K=32, 9 bins, width 20.
#define BB 8
#define NN 2048
#define KK 32

// ===========================================================================
// Exactly-rounded f32 helpers (R15): native f32 _rn intrinsics. By Figueroa's
// theorem, (float)((double)a op (double)b) == correctly-rounded f32 op for
// +,-,*,/,sqrt — verified bit-identical on HW in R15 (absmax unchanged).
// ===========================================================================
__device__ __forceinline__ float fadd(float a, float b){ return __fadd_rn(a, b); }
__device__ __forceinline__ float fsub(float a, float b){ return __fsub_rn(a, b); }
__device__ __forceinline__ float fmul(float a, float b){ return __fmul_rn(a, b); }
__device__ __forceinline__ float fdiv(float a, float b){ return __fdiv_rn(a, b); }
__device__ __forceinline__ float fsqrtf32(float a){ return __fsqrt_rn(a); }

// ===========================================================================
// LAPACK 3.12 single-precision helpers, gfortran -ffp-contract=fast model.
// ===========================================================================
__device__ float slapy2f(float x, float y) {
    float xa = fabsf(x), ya = fabsf(y);
    float w = fmaxf(xa, ya), z = fminf(xa, ya);
    if (z == 0.0f) return w;
    float q = fdiv(z, w);
    return fmul(w, fsqrtf32(fmaf(q, q, 1.0f)));
}

__device__ void slartgf(float f, float g, float& c, float& s, float& r) {
    if (g == 0.0f) { c = 1.0f; s = 0.0f; r = f; }
    else if (f == 0.0f) { c = 0.0f; s = copysignf(1.0f, g); r = fabsf(g); }
    else {
        float d = fsqrtf32(fmaf(f, f, fmul(g, g)));
        c = fdiv(fabsf(f), d);
        r = copysignf(d, f);
        s = fdiv(g, r);
    }
}

__device__ void slas2f(float f, float g, float h, float& ssmin, float& ssmax) {
    float fa = fabsf(f), ga = fabsf(g), ha = fabsf(h);
    float fhmn = fminf(fa, ha), fhmx = fmaxf(fa, ha);
    if (fhmn == 0.0f) {
        ssmin = 0.0f;
        if (fhmx == 0.0f) ssmax = ga;
        else {
            float mx = fmaxf(fhmx, ga), mn = fminf(fhmx, ga);
            float q = fdiv(mn, mx);
            ssmax = fmul(mx, fsqrtf32(fmaf(q, q, 1.0f)));
        }
    } else {
        if (ga < fhmx) {
            float as = fadd(1.0f, fdiv(fhmn, fhmx));
            float at = fdiv(fsub(fhmx, fhmn), fhmx);
            float q = fdiv(ga, fhmx); float au = fmul(q, q);
            float c = fdiv(2.0f, fadd(fsqrtf32(fmaf(as, as, au)),
                                      fsqrtf32(fmaf(at, at, au))));
            ssmin = fmul(fhmn, c); ssmax = fdiv(fhmx, c);
        } else {
            float au = fdiv(fhmx, ga);
            if (au == 0.0f) { ssmin = fdiv(fmul(fhmn, fhmx), ga); ssmax = ga; }
            else {
                float as = fadd(1.0f, fdiv(fhmn, fhmx));
                float at = fdiv(fsub(fhmx, fhmn), fhmx);
                float t1 = fmul(as, au), t2 = fmul(at, au);
                float c = fdiv(1.0f, fadd(fsqrtf32(fmaf(t1, t1, 1.0f)),
                                          fsqrtf32(fmaf(t2, t2, 1.0f))));
                ssmin = fmul(fmul(fhmn, c), au); ssmin = fadd(ssmin, ssmin);
                ssmax = fdiv(ga, fadd(c, c));
            }
        }
    }
}

__device__ void slasv2f(float f, float g, float h,
                        float& ssmin, float& ssmax,
                        float& snr, float& csr, float& snl, float& csl) {
    const float eps = 5.9604644775390625e-08f;
    float ft = f, fa = fabsf(f), ht = h, ha = fabsf(h);
    int pmax = 1;
    bool swp = (ha > fa);
    if (swp) { pmax = 3; float t = ft; ft = ht; ht = t; t = fa; fa = ha; ha = t; }
    float gt = g, ga = fabsf(gt);
    float clt = 0.f, crt = 0.f, slt = 0.f, srt = 0.f;
    if (ga == 0.0f) {
        ssmin = ha; ssmax = fa; clt = 1.0f; crt = 1.0f; slt = 0.0f; srt = 0.0f;
    } else {
        bool gasmal = true;
        if (ga > fa) {
            pmax = 2;
            if (fdiv(fa, ga) < eps) {
                gasmal = false;
                ssmax = ga;
                ssmin = (ha > 1.0f) ? fdiv(fa, fdiv(ga, ha)) : fmul(fdiv(fa, ga), ha);
                clt = 1.0f; slt = fdiv(ht, gt); srt = 1.0f; crt = fdiv(ft, gt);
            }
        }
        if (gasmal) {
            float dd = fsub(fa, ha);
            float l = (dd == fa) ? 1.0f : fdiv(dd, fa);
            float mm = fdiv(gt, ft);
            float t = fsub(2.0f, l);
            float m2 = fmul(mm, mm);
            float s = fsqrtf32(fmaf(t, t, m2));
            float r = (l == 0.0f) ? fabsf(mm) : fsqrtf32(fmaf(l, l, m2));
            float a = fmul(0.5f, fadd(s, r));
            ssmin = fdiv(ha, a);
            ssmax = fmul(fa, a);
            if (m2 == 0.0f) {
                t = (l == 0.0f) ? fmul(copysignf(2.0f, ft), copysignf(1.0f, gt))
                                : fadd(fdiv(gt, copysignf(dd, ft)), fdiv(mm, t));
            } else {
                t = fmul(fadd(fdiv(mm, fadd(s, t)), fdiv(mm, fadd(r, l))), fadd(1.0f, a));
            }
            float l2 = fsqrtf32(fmaf(t, t, 4.0f));
            crt = fdiv(2.0f, l2); srt = fdiv(t, l2);
            clt = fdiv(fmaf(srt, mm, crt), a);
            slt = fdiv(fmul(fdiv(ht, ft), srt), a);
        }
    }
    if (swp) { csl = srt; snl = crt; csr = slt; snr = clt; }
    else     { csl = clt; snl = slt; csr = crt; snr = srt; }
    float tsign = 0.0f;
    if (pmax == 1) tsign = fmul(fmul(copysignf(1.f, csr), copysignf(1.f, csl)), copysignf(1.f, f));
    if (pmax == 2) tsign = fmul(fmul(copysignf(1.f, snr), copysignf(1.f, csl)), copysignf(1.f, g));
    if (pmax == 3) tsign = fmul(fmul(copysignf(1.f, snr), copysignf(1.f, snl)), copysignf(1.f, h));
    ssmax = copysignf(fabsf(ssmax), tsign);
    ssmin = copysignf(fabsf(ssmin), fmul(tsign, fmul(copysignf(1.f, f), copysignf(1.f, h))));
}

// slasr 'L','V' rotation on vt rows lo,hi (1-indexed), fma-contracted
__device__ __forceinline__ void rot_rowsf(float vt[4][4], int lo, int hi, float cc, float ss) {
    #pragma unroll
    for (int c = 1; c <= 3; ++c) {
        float t = vt[hi][c];
        vt[hi][c] = fmaf(cc, t, -fmul(ss, vt[lo][c]));
        vt[lo][c] = fmaf(ss, t, fmul(cc, vt[lo][c]));
    }
}

// sbdsqr for n=3 upper bidiagonal — R16/R18 array version (R17's select-chain
// rewrite regressed ~12 µs; the small hot stack arrays are L1-resident).
// R9 note: idir2-shifted VT pairing is (COSL, -SINL) — do not touch.
__device__ void bdsqr3f(float* d, float* e, float vt[4][4]) {
    const float eps  = 5.9604644775390625e-08f;
    const float unfl = 1.1754943508222875e-38f;
    const int n = 3;
    const float tol = fmul(10.0f, eps);
    float thresh;
    {
        float sminoa = fabsf(d[1]);
        if (sminoa != 0.0f) {
            float mu = sminoa;
            for (int i = 2; i <= n; ++i) {
                mu = fmul(fabsf(d[i]), fdiv(mu, fadd(mu, fabsf(e[i - 1]))));
                sminoa = fminf(sminoa, mu);
                if (sminoa == 0.0f) break;
            }
        }
        sminoa = fdiv(sminoa, fsqrtf32(3.0f));
        thresh = fmaxf(fmul(tol, sminoa), fmul(54.0f, unfl));
    }
    int m = n, iter = 0, oldll = -1, oldm = -1, idir = 0;
    float sminl = 0.0f;
    while (m > 1) {
        if (iter > 54) break;
        float smax = fabsf(d[m]);
        int ll = 0; bool split = false;
        for (int lll = 1; lll <= m - 1; ++lll) {
            int l2 = m - lll;
            float abss = fabsf(d[l2]), abse = fabsf(e[l2]);
            if (abse <= thresh) { ll = l2; split = true; break; }
            smax = fmaxf(smax, fmaxf(abss, abse));
        }
        if (split) {
            e[ll] = 0.0f;
            if (ll == m - 1) { m = m - 1; continue; }
            ll = ll + 1;
        } else ll = 1;
        if (ll == m - 1) {
            float sigmn, sigmx, sinr, cosr, sinl, cosl;
            slasv2f(d[m - 1], e[m - 1], d[m], sigmn, sigmx, sinr, cosr, sinl, cosl);
            d[m - 1] = sigmx; e[m - 1] = 0.0f; d[m] = sigmn;
            #pragma unroll
            for (int c = 1; c <= 3; ++c) {
                float t = fmaf(cosr, vt[m - 1][c], fmul(sinr, vt[m][c]));
                vt[m][c] = fmaf(cosr, vt[m][c], -fmul(sinr, vt[m - 1][c]));
                vt[m - 1][c] = t;
            }
            m -= 2; continue;
        }
        if (ll > oldm || m < oldll)
            idir = (fabsf(d[ll]) >= fabsf(d[m])) ? 1 : 2;
        bool deflated = false;
        if (idir == 1) {
            if (fabsf(e[m - 1]) <= fmul(tol, fabsf(d[m]))) { e[m - 1] = 0.0f; continue; }
            float mu = fabsf(d[ll]); sminl = mu;
            for (int lll = ll; lll <= m - 1; ++lll) {
                if (fabsf(e[lll]) <= fmul(tol, mu)) { e[lll] = 0.0f; deflated = true; break; }
                mu = fmul(fabsf(d[lll + 1]), fdiv(mu, fadd(mu, fabsf(e[lll]))));
                sminl = fminf(sminl, mu);
            }
        } else {
            if (fabsf(e[ll]) <= fmul(tol, fabsf(d[ll]))) { e[ll] = 0.0f; continue; }
            float mu = fabsf(d[m]); sminl = mu;
            for (int lll = m - 1; lll >= ll; --lll) {
                if (fabsf(e[lll]) <= fmul(tol, mu)) { e[lll] = 0.0f; deflated = true; break; }
                mu = fmul(fabsf(d[lll]), fdiv(mu, fadd(mu, fabsf(e[lll]))));
                sminl = fminf(sminl, mu);
            }
        }
        if (deflated) continue;
        oldll = ll; oldm = m;
        float shift = 0.0f, rr;
        if (!(fmul(fmul(3.0f, tol), fdiv(sminl, smax)) <= fmaxf(eps, fmul(0.01f, tol)))) {
            float sll;
            if (idir == 1) { sll = fabsf(d[ll]); slas2f(d[m - 1], e[m - 1], d[m], shift, rr); }
            else           { sll = fabsf(d[m]);  slas2f(d[ll], e[ll], d[ll + 1], shift, rr); }
            if (sll > 0.0f) { float q = fdiv(shift, sll); if (fmul(q, q) < eps) shift = 0.0f; }
        }
        iter += m - ll;
        float wc[4], ws[4];
        if (shift == 0.0f) {
            if (idir == 1) {
                float cs = 1.0f, oldcs = 1.0f, sn = 0.0f, oldsn = 0.0f, r2;
                for (int i = ll; i <= m - 1; ++i) {
                    slartgf(fmul(d[i], cs), e[i], cs, sn, r2);
                    if (i > ll) e[i - 1] = fmul(oldsn, r2);
                    slartgf(fmul(oldcs, r2), fmul(d[i + 1], sn), oldcs, oldsn, d[i]);
                    wc[i - ll + 1] = cs; ws[i - ll + 1] = sn;
                }
                float h = fmul(d[m], cs); d[m] = fmul(h, oldcs); e[m - 1] = fmul(h, oldsn);
                if (fabsf(e[m - 1]) <= thresh) e[m - 1] = 0.0f;
                for (int j = 1; j <= m - ll; ++j) rot_rowsf(vt, ll + j - 1, ll + j, wc[j], ws[j]);
            } else {
                float cs = 1.0f, oldcs = 1.0f, sn = 0.0f, oldsn = 0.0f, r2;
                for (int i = m; i >= ll + 1; --i) {
                    slartgf(fmul(d[i], cs), e[i - 1], cs, sn, r2);
                    if (i < m) e[i] = fmul(oldsn, r2);
                    slartgf(fmul(oldcs, r2), fmul(d[i - 1], sn), oldcs, oldsn, d[i]);
                    wc[i - ll] = oldcs; ws[i - ll] = -oldsn;
                }
                float h = fmul(d[ll], cs); d[ll] = fmul(h, oldcs); e[ll] = fmul(h, oldsn);
                if (fabsf(e[ll]) <= thresh) e[ll] = 0.0f;
                for (int j = m - ll; j >= 1; --j) rot_rowsf(vt, ll + j - 1, ll + j, wc[j], ws[j]);
            }
        } else {
            if (idir == 1) {
                float fq = fmul(fsub(fabsf(d[ll]), shift),
                                fadd(copysignf(1.0f, d[ll]), fdiv(shift, d[ll])));
                float g = e[ll], cosr, sinr, cosl, sinl, r2;
                for (int i = ll; i <= m - 1; ++i) {
                    slartgf(fq, g, cosr, sinr, r2);
                    if (i > ll) e[i - 1] = r2;
                    float di = d[i], ei = e[i], dip = d[i + 1];
                    fq         = fmaf(cosr, di, fmul(sinr, ei));
                    float ei_n = fmaf(cosr, ei, -fmul(sinr, di));
                    g = fmul(sinr, dip);
                    float dip_n = fmul(cosr, dip);
                    slartgf(fq, g, cosl, sinl, r2);
                    d[i] = r2;
                    fq       = fmaf(cosl, ei_n, fmul(sinl, dip_n));
                    d[i + 1] = fmaf(cosl, dip_n, -fmul(sinl, ei_n));
                    e[i] = ei_n;
                    if (i < m - 1) { g = fmul(sinl, e[i + 1]); e[i + 1] = fmul(cosl, e[i + 1]); }
                    wc[i - ll + 1] = cosr; ws[i - ll + 1] = sinr;
                }
                e[m - 1] = fq;
                if (fabsf(e[m - 1]) <= thresh) e[m - 1] = 0.0f;
                for (int j = 1; j <= m - ll; ++j) rot_rowsf(vt, ll + j - 1, ll + j, wc[j], ws[j]);
            } else {
                float fq = fmul(fsub(fabsf(d[m]), shift),
                                fadd(copysignf(1.0f, d[m]), fdiv(shift, d[m])));
                float g = e[m - 1], cosr, sinr, cosl, sinl, r2;
                for (int i = m; i >= ll + 1; --i) {
                    slartgf(fq, g, cosr, sinr, r2);
                    if (i < m) e[i] = r2;
                    float di = d[i], em = e[i - 1], dim = d[i - 1];
                    fq         = fmaf(cosr, di, fmul(sinr, em));
                    float em_n = fmaf(cosr, em, -fmul(sinr, di));
                    g = fmul(sinr, dim);
                    float dim_n = fmul(cosr, dim);
                    slartgf(fq, g, cosl, sinl, r2);
                    d[i] = r2;
                    fq       = fmaf(cosl, em_n, fmul(sinl, dim_n));
                    d[i - 1] = fmaf(cosl, dim_n, -fmul(sinl, em_n));
                    e[i - 1] = em_n;
                    if (i > ll + 1) { g = fmul(sinl, e[i - 2]); e[i - 2] = fmul(cosl, e[i - 2]); }
                    wc[i - ll] = cosl; ws[i - ll] = -sinl;   // R9-verified pairing
                }
                e[ll] = fq;
                if (fabsf(e[ll]) <= thresh) e[ll] = 0.0f;
                for (int j = m - ll; j >= 1; --j) rot_rowsf(vt, ll + j - 1, ll + j, wc[j], ws[j]);
            }
        }
    }
    for (int i = 1; i <= n; ++i) {
        if (d[i] < 0.0f) {
            d[i] = -d[i];
            for (int c = 1; c <= 3; ++c) vt[i][c] = -vt[i][c];
        }
    }
    for (int i = 1; i <= n - 1; ++i) {
        int isub = 1; float smin2 = d[1];
        for (int j = 2; j <= n + 1 - i; ++j)
            if (d[j] <= smin2) { isub = j; smin2 = d[j]; }
        int tgt = n + 1 - i;
        if (isub != tgt) {
            d[isub] = d[tgt]; d[tgt] = smin2;
            for (int c = 1; c <= 3; ++c) { float t = vt[isub][c]; vt[isub][c] = vt[tgt][c]; vt[tgt][c] = t; }
        }
    }
}

// ===========================================================================
// Kernel 0: d2 in f32 (separate — R16's knn-inline regressed knn 81->93)
// ===========================================================================
__global__ void d2_kernel(const float* __restrict__ x, float* __restrict__ d2) {
    int t = blockIdx.x * blockDim.x + threadIdx.x;
    if (t >= BB * NN) return;
    int b = t / NN, n = t % NN;
    const float* xb = x + b * 3 * NN;
    float xv = xb[n], yv = xb[NN + n], zv = xb[2 * NN + n];
    d2[t] = fadd(fadd(fmul(xv, xv), fmul(yv, yv)), fmul(zv, zv));
}

// ===========================================================================
// Kernel 1: KNN — R22: exact restore of the R19 measured-best variant
// (65.2 µs). R20/R21 post-mortem: the branchless double-cascade chained 24
// dependent DPP ops per iteration and regressed to 67.3 µs @ 70% busy —
// R19's ballot/ffs fast path (single 12-op cascade + cheap SALU excursion,
// rare-tie fallback cascade) is the better issue-vs-latency point.
//
// Protocol per iteration:
//   1. 6-stage u32 DPP max on the VALUE word l0h (12 insts)
//   2. ballot(l0h == wbest); single bit (common): winner lane = ffs (SALU),
//      wlow = readlane(l0l, lane)
//   3. rare value-tie: masked u32 DPP max on l0l — exactly the u64-max
//      semantics (max hi, then max lo among max-hi lanes)
// amw = (l0l == wlow) suffices: keylow = 2047-j is globally unique across
// lanes. Refill trigger l0h==0 is safe (finite => sortable > 0x007FFFFF).
// Extraction sequence bit-identical to R13.
// ===========================================================================
__device__ __forceinline__ unsigned int f32_sortable(float f) {
    unsigned int b = __float_as_uint(f);
    return b ^ ((unsigned int)((int)b >> 31) | 0x80000000u);
}
__device__ __forceinline__ float sortable_f32(unsigned int s) {
    unsigned int b = s ^ (~(unsigned int)((int)s >> 31) | 0x80000000u);
    return __uint_as_float(b);
}

template <int CTRL, int RM>
__device__ __forceinline__ unsigned int dpp_umax32(unsigned int v) {
    unsigned int nv = (unsigned int)__builtin_amdgcn_update_dpp(0, (int)v, CTRL, RM, 0xF, false);
    return nv > v ? nv : v;
}

// full 6-stage cascade: lane 63 ends with the wave-wide max
__device__ __forceinline__ unsigned int wave_umax32(unsigned int v) {
    v = dpp_umax32<0x111, 0xF>(v);   // row_shr:1
    v = dpp_umax32<0x112, 0xF>(v);   // row_shr:2
    v = dpp_umax32<0x114, 0xF>(v);   // row_shr:4
    v = dpp_umax32<0x118, 0xF>(v);   // row_shr:8
    v = dpp_umax32<0x142, 0xA>(v);   // row_bcast:15 -> rows 1,3
    v = dpp_umax32<0x143, 0xC>(v);   // row_bcast:31 -> rows 2,3
    return v;
}

// Pop the lane's best remaining candidate from vals (value desc, slot asc),
// clear it, and return the packed u64 merge key. All indices static.
__device__ __forceinline__ unsigned long long pop_best(unsigned int (&vals)[32], int lane) {
    unsigned int m = vals[0];
    #pragma unroll
    for (int s = 1; s < 32; ++s) m = (vals[s] > m) ? vals[s] : m;   // v_max_u32
    int bs = 0;
    #pragma unroll
    for (int s = 31; s >= 0; --s) if (vals[s] == m) bs = s;          // first match
    #pragma unroll
    for (int s = 0; s < 32; ++s) vals[s] = (s == bs) ? 0u : vals[s]; // clear
    int j = bs * 64 + lane;
    return ((unsigned long long)m << 32) | (unsigned int)(2047 - j);
}

__global__ void __launch_bounds__(256) knn_kernel(const float* __restrict__ x,
                                                  const float* __restrict__ d2,
                                                  int* __restrict__ idx) {
    int lane = threadIdx.x & 63;
    int wid  = threadIdx.x >> 6;
    int row  = blockIdx.x * 4 + wid;
    int b = row / NN, i = row % NN;
    const float* xb  = x  + b * 3 * NN;
    const float* d2b = d2 + b * NN;

    float xi = xb[i], yi = xb[NN + i], zi = xb[2 * NN + i];
    float d2i = d2b[i];

    // 32 candidates per lane, sortable-u32 encoded, static register indexing.
    unsigned int vals[32];
    #pragma unroll
    for (int s = 0; s < 32; ++s) {
        int j = s * 64 + lane;
        float dot = fmul(xi, xb[j]);
        dot = fmaf(yi, xb[NN + j], dot);
        dot = fmaf(zi, xb[2 * NN + j], dot);
        float v = fsub(fsub(fmul(2.0f, dot), d2i), d2b[j]);
        vals[s] = f32_sortable(v);
    }

    // ---- build the 4-deep lookahead mini-list (hi/lo u32 named scalars)
    unsigned long long p;
    p = pop_best(vals, lane);
    unsigned int l0h = (unsigned int)(p >> 32), l0l = (unsigned int)p;
    p = pop_best(vals, lane);
    unsigned int l1h = (unsigned int)(p >> 32), l1l = (unsigned int)p;
    p = pop_best(vals, lane);
    unsigned int l2h = (unsigned int)(p >> 32), l2l = (unsigned int)p;
    p = pop_best(vals, lane);
    unsigned int l3h = (unsigned int)(p >> 32), l3l = (unsigned int)p;

    int* idxrow = idx + row * KK;
    unsigned int c1v = 0, c2v = 0, c3v = 0, c31v = 0, c32v = 0;
    int c1i = 0, c2i = 0, c3i = 0, c31i = 0, c32i = 0;

    #pragma unroll 1
    for (int t = 0; t < KK + 1; ++t) {      // 33 ranks (32 + boundary probe)
        // rare refill: some lane consumed its whole lookahead (won 4+ times).
        // l0h==0 iff sentinel (finite values => sortable > 0x007FFFFF > 0).
        if (__any(l0h == 0u)) {
            bool need = (l0h == 0u);
            unsigned int m = vals[0];
            #pragma unroll
            for (int s = 1; s < 32; ++s) m = (vals[s] > m) ? vals[s] : m;
            int bs = 0;
            #pragma unroll
            for (int s = 31; s >= 0; --s) if (vals[s] == m) bs = s;
            #pragma unroll
            for (int s = 0; s < 32; ++s)
                vals[s] = (need && s == bs) ? 0u : vals[s];
            unsigned int enth = m;
            unsigned int entl = (unsigned int)(2047 - (bs * 64 + lane));
            l0h = need ? enth : l0h;
            l0l = need ? entl : l0l;
        }

        // wave max of the VALUE word (32-bit DPP cascade)
        unsigned int wbest = (unsigned int)__builtin_amdgcn_readlane(
            (int)wave_umax32(l0h), 63);

        // winner lane: unique-match fast path via ballot+ffs
        unsigned long long mask = __ballot(l0h == wbest);
        unsigned int wlow;
        if (__popcll(mask) == 1) {
            int wl = __ffsll((long long)mask) - 1;
            wlow = (unsigned int)__builtin_amdgcn_readlane((int)l0l, wl);
        } else {
            // exact value tie across lanes (rare): max l0l among tied lanes
            unsigned int tl = (l0h == wbest) ? l0l : 0u;
            wlow = (unsigned int)__builtin_amdgcn_readlane(
                (int)wave_umax32(tl), 63);
        }
        int wj = 2047 - (int)(wlow & 0x7FFu);

        // winner lane pops its head (keylow globally unique => 1 cmp).
        bool amw = (l0l == wlow);
        l0h = amw ? l1h : l0h;  l0l = amw ? l1l : l0l;
        l1h = amw ? l2h : l1h;  l1l = amw ? l2l : l1l;
        l2h = amw ? l3h : l2h;  l2l = amw ? l3l : l2l;
        l3h = amw ? 0u  : l3h;  l3l = amw ? 0u  : l3l;

        // record: ranks 1,2,3,31,32 are deferred for the near-tie probes
        if (t == 1)           { c1v = wbest;  c1i = wj; }
        else if (t == 2)      { c2v = wbest;  c2i = wj; }
        else if (t == 3)      { c3v = wbest;  c3i = wj; }
        else if (t == KK - 1) { c31v = wbest; c31i = wj; }
        else if (t == KK)     { c32v = wbest; c32i = wj; }
        else if (lane == 0)   idxrow[t] = wj;
    }

    if (lane == 0) {
        const float TIE = 4e-7f;
        float r1  = sortable_f32(c1v),  r2  = sortable_f32(c2v), r3 = sortable_f32(c3v);
        float r31 = sortable_f32(c31v), r32 = sortable_f32(c32v);
        if (fabsf(r1 - r2) < TIE) { int ti = c1i; c1i = c2i; c2i = ti; float tv = r1; r1 = r2; r2 = tv; }
        if (fabsf(r2 - r3) < TIE) { int ti = c2i; c2i = c3i; c3i = ti; float tv = r2; r2 = r3; r3 = tv; }
        idxrow[1] = c1i; idxrow[2] = c2i; idxrow[3] = c3i;
        idxrow[KK - 1] = (fabsf(r31 - r32) < TIE) ? c32i : c31i;
    }
}

// ===========================================================================
// Kernel 2: sgesdd emulation + fused vote precompute (R19 structure:
// coordinates loaded once into A0/A1/A2, bit-identical op order).
// ===========================================================================
__global__ void eig_kernel(const float* __restrict__ x, const int* __restrict__ idx,
                           float4* __restrict__ votes, int* __restrict__ binsq) {
    int t = blockIdx.x * blockDim.x + threadIdx.x;
    if (t >= BB * NN) return;
    int b = t / NN;
    const float* xb = x + b * 3 * NN;
    const int* id = idx + t * KK;

    float A0[KK], A1[KK], A2[KK];
    #pragma unroll
    for (int j = 0; j < KK; ++j) {
        int n = id[j];
        A0[j] = xb[n];
        A1[j] = xb[NN + n];
        A2[j] = xb[2 * NN + n];
    }
    float s0 = 0.f, s1 = 0.f, s2 = 0.f;
    #pragma unroll
    for (int j = 0; j < KK; ++j) {
        s0 = fadd(s0, A0[j]); s1 = fadd(s1, A1[j]); s2 = fadd(s2, A2[j]);
    }
    float m0 = fdiv(s0, 32.f), m1 = fdiv(s1, 32.f), m2 = fdiv(s2, 32.f);
    #pragma unroll
    for (int j = 0; j < KK; ++j) {
        A0[j] = fsub(A0[j], m0);
        A1[j] = fsub(A1[j], m1);
        A2[j] = fsub(A2[j], m2);
    }

    // ---- sgeqr2 with slarf1f (i = 0: col0 reflector, update col1,col2)
    {
        float alpha = A0[0];
        double nacc = 0.0;
        #pragma unroll
        for (int r = 1; r < KK; ++r) nacc += (double)A0[r] * (double)A0[r];
        float xnorm = (float)sqrt(nacc);
        if (xnorm != 0.0f) {
            float beta = -copysignf(slapy2f(alpha, xnorm), alpha);
            float tau  = fdiv(fsub(beta, alpha), beta);
            float scal = fdiv(1.0f, fsub(alpha, beta));
            #pragma unroll
            for (int r = 1; r < KK; ++r) A0[r] = fmul(A0[r], scal);
            A0[0] = beta;
            // j = 1
            {
                float acc = 0.0f;
                #pragma unroll
                for (int r = 1; r < KK; ++r) acc = fmaf(A0[r], A1[r], acc);
                float w = fadd(acc, A1[0]);
                A1[0] = fmaf(-tau, w, A1[0]);
                float temp = fmul(-tau, w);
                #pragma unroll
                for (int r = 1; r < KK; ++r) A1[r] = fmaf(A0[r], temp, A1[r]);
            }
            // j = 2
            {
                float acc = 0.0f;
                #pragma unroll
                for (int r = 1; r < KK; ++r) acc = fmaf(A0[r], A2[r], acc);
                float w = fadd(acc, A2[0]);
                A2[0] = fmaf(-tau, w, A2[0]);
                float temp = fmul(-tau, w);
                #pragma unroll
                for (int r = 1; r < KK; ++r) A2[r] = fmaf(A0[r], temp, A2[r]);
            }
        }
    }
    // ---- i = 1: col1 reflector, update col2
    {
        float alpha = A1[1];
        double nacc = 0.0;
        #pragma unroll
        for (int r = 2; r < KK; ++r) nacc += (double)A1[r] * (double)A1[r];
        float xnorm = (float)sqrt(nacc);
        if (xnorm != 0.0f) {
            float beta = -copysignf(slapy2f(alpha, xnorm), alpha);
            float tau  = fdiv(fsub(beta, alpha), beta);
            float scal = fdiv(1.0f, fsub(alpha, beta));
            #pragma unroll
            for (int r = 2; r < KK; ++r) A1[r] = fmul(A1[r], scal);
            A1[1] = beta;
            // j = 2
            {
                float acc = 0.0f;
                #pragma unroll
                for (int r = 2; r < KK; ++r) acc = fmaf(A1[r], A2[r], acc);
                float w = fadd(acc, A2[1]);
                A2[1] = fmaf(-tau, w, A2[1]);
                float temp = fmul(-tau, w);
                #pragma unroll
                for (int r = 2; r < KK; ++r) A2[r] = fmaf(A1[r], temp, A2[r]);
            }
        }
    }
    // ---- i = 2: col2 reflector (no trailing columns)
    {
        float alpha = A2[2];
        double nacc = 0.0;
        #pragma unroll
        for (int r = 3; r < KK; ++r) nacc += (double)A2[r] * (double)A2[r];
        float xnorm = (float)sqrt(nacc);
        if (xnorm != 0.0f) {
            float beta = -copysignf(slapy2f(alpha, xnorm), alpha);
            float scal = fdiv(1.0f, fsub(alpha, beta));
            #pragma unroll
            for (int r = 3; r < KK; ++r) A2[r] = fmul(A2[r], scal);
            A2[2] = beta;
        }
    }
    float B11 = A0[0], B12 = A1[0], B13 = A2[0];
    float B22 = A1[1], B23 = A2[1], B33 = A2[2];

    // ---- sgebd2 with slarf1f
    float d[4], e[3];
    float taup = 0.0f, v2p = 0.0f;
    d[1] = B11;
    float B32 = 0.0f;
    if (B13 != 0.0f) {
        float xn = fsqrtf32(fmul(B13, B13));
        float beta = -copysignf(slapy2f(B12, xn), B12);
        taup = fdiv(fsub(beta, B12), beta);
        float scal = fdiv(1.0f, fsub(B12, beta));
        v2p = fmul(B13, scal);
        e[1] = beta;
        float w2 = fadd(fmul(B23, v2p), B22);
        float w3 = fmul(B33, v2p);
        B22 = fmaf(-taup, w2, B22);
        B32 = fmul(-taup, w3);
        float tmp = fmul(-taup, v2p);
        B23 = fmaf(w2, tmp, B23);
        B33 = fmaf(w3, tmp, B33);
    } else e[1] = B12;
    if (B32 != 0.0f) {
        float xn = fsqrtf32(fmul(B32, B32));
        float beta = -copysignf(slapy2f(B22, xn), B22);
        float tauq = fdiv(fsub(beta, B22), beta);
        float scal = fdiv(1.0f, fsub(B22, beta));
        float v2 = fmul(B32, scal);
        d[2] = beta;
        float w = fadd(fmul(v2, B33), B23);
        B23 = fmaf(-tauq, w, B23);
        float tmp = fmul(-tauq, w);
        B33 = fmaf(v2, tmp, B33);
    } else d[2] = B22;
    e[2] = B23;
    d[3] = B33;

    // ---- sbdsqr with VT = I
    float vt[4][4];
    for (int r = 1; r <= 3; ++r)
        for (int c = 1; c <= 3; ++c) vt[r][c] = (r == c) ? 1.0f : 0.0f;
    bdsqr3f(d, e, vt);

    // ---- sormbr 'P','R','T' via slarf1f
    if (taup != 0.0f) {
        float tmp = fmul(-taup, v2p);
        for (int r = 1; r <= 3; ++r) {
            float w = fadd(fmul(vt[r][3], v2p), vt[r][2]);
            vt[r][2] = fmaf(-taup, w, vt[r][2]);
            vt[r][3] = fmaf(w, tmp, vt[r][3]);
        }
    }

    int im = 1;
    if (d[2] > d[im]) im = 2;
    if (d[3] > d[im]) im = 3;
    float gx = vt[im][1];
    float gy = vt[im][2];
    float gz = vt[im][3];
    float m  = fsqrtf32(d[im]);

    // ---- fused vote precompute (identical ops to the old vote_kernel)
    const float r2d = (float)(180.0 / M_PI);
    float zen = (float)acos((double)gz);
    float zd  = fmul(zen, r2d);
    float q0  = fdiv(gy, gx);
    float azr = (float)atan((double)q0);
    float ad  = fmul(azr, r2d);

    float a0 = (zd != zd) ? -2147483648.0f : (float)(int)zd;
    float a1 = (ad != ad) ? -2147483648.0f : (float)(int)ad;

    float v1s[2], v2s[2]; int bis[2];
    #pragma unroll
    for (int c = 0; c < 2; ++c) {
        float a = (c == 0) ? a0 : a1;
        if (a < 0.0f) a = fadd(a, 180.0f);
        float tq = fdiv(a, 20.0f);
        float t2 = fsub(tq, 0.5f);
        float fb = floorf(t2);
        float bin = fmodf(fb, 9.0f); if (bin != 0.0f && bin < 0.0f) bin = fadd(bin, 9.0f);
        float b1 = fadd(bin, 1.0f);
        float b1m = fmodf(b1, 9.0f);
        float fc = fmul(20.0f, fadd(b1m, 0.5f));
        float df = fsub(fc, a);
        float rm = fmodf(df, 180.0f); if (rm != 0.0f && rm < 0.0f) rm = fadd(rm, 180.0f);
        v1s[c] = fdiv(fmul(m, rm), 20.0f);
        float sc = fmul(20.0f, fadd(bin, 0.5f));
        float ds = fsub(a, sc);
        float rm2 = fmodf(ds, 180.0f); if (rm2 != 0.0f && rm2 < 0.0f) rm2 = fadd(rm2, 180.0f);
        v2s[c] = fdiv(fmul(m, rm2), 20.0f);
        bis[c] = (int)bin;
    }
    votes[t] = make_float4(v1s[0], v2s[0], v1s[1], v2s[1]);
    binsq[t] = bis[0] | (bis[1] << 8);
}

// ===========================================================================
// Kernel 3: HOG accumulation (R16 static-register version, R19 unroll-8 —
// bit-identical j-ascending add order, fully static indices => registers).
// ===========================================================================
__global__ void hist_kernel(const int* __restrict__ idx, const float4* __restrict__ votes,
                            const int* __restrict__ binsq, float* __restrict__ out) {
    int t = blockIdx.x * blockDim.x + threadIdx.x;
    if (t >= BB * NN) return;
    int b = t / NN, n = t % NN;
    const int* id = idx + t * KK;

    float h1[9][2], h2[9][2];
    #pragma unroll
    for (int q = 0; q < 9; ++q) { h1[q][0] = h1[q][1] = 0.f; h2[q][0] = h2[q][1] = 0.f; }

    #pragma unroll 8
    for (int j = 0; j < KK; ++j) {
        int jj = b * NN + id[j];
        float4 v = votes[jj];
        int bp = binsq[jj];
        int bi0 = bp & 0xFF, bi1 = bp >> 8;
        int b20 = bi0 + 1; if (b20 >= 9) b20 -= 9;
        int b21 = bi1 + 1; if (b21 >= 9) b21 -= 9;
        #pragma unroll
        for (int q = 0; q < 9; ++q) {
            h1[q][0] = (bi0 == q) ? fadd(h1[q][0], v.x) : h1[q][0];
            h2[q][0] = (b20 == q) ? fadd(h2[q][0], v.y) : h2[q][0];
            h1[q][1] = (bi1 == q) ? fadd(h1[q][1], v.z) : h1[q][1];
            h2[q][1] = (b21 == q) ? fadd(h2[q][1], v.w) : h2[q][1];
        }
    }

    float* o = out + b * (18 * NN) + n * 18;
    #pragma unroll
    for (int c = 0; c < 2; ++c) {
        float hist[9];
        #pragma unroll
        for (int q = 0; q < 9; ++q) hist[q] = fadd(h1[q][c], h2[q][c]);
        float acc = 0.0f;
        #pragma unroll
        for (int q = 0; q < 9; ++q) acc = fadd(acc, fmul(hist[q], hist[q]));
        float nr = fsqrtf32(acc);
        float den = fmaxf(nr, 1e-12f);
        #pragma unroll
        for (int q = 0; q < 9; ++q) o[q * 2 + c] = fdiv(hist[q], den);
    }
}

// ===========================================================================
extern "C" void kernel_launch(void* const* d_in, const int* in_sizes, int n_in,
                              void* d_out, int out_size, void* d_ws, size_t ws_size,
                              hipStream_t stream) {
    const float* x = (const float*)d_in[0];
    float* out = (float*)d_out;

    char* ws = (char*)d_ws;
    size_t off = 0;
    int* idx = (int*)(ws + off);         off += (size_t)BB * NN * KK * sizeof(int);
    float* d2 = (float*)(ws + off);      off += (size_t)BB * NN * sizeof(float);
    float4* votes = (float4*)(ws + off); off += (size_t)BB * NN * sizeof(float4);
    int* binsq = (int*)(ws + off);

    d2_kernel  <<<(BB * NN + 63) / 64, 64, 0, stream>>>(x, d2);
    knn_kernel <<<BB * NN / 4, 256, 0, stream>>>(x, d2, idx);
    eig_kernel <<<(BB * NN + 63) / 64, 64, 0, stream>>>(x, idx, votes, binsq);
    hist_kernel<<<(BB * NN + 63) / 64, 64, 0, stream>>>(idx, votes, binsq, out);
}